// Round 15
// baseline (706.459 us; speedup 1.0000x reference)
//
#include <hip/hip_runtime.h>
#include <hip/hip_bf16.h>

#define HDIM 2048
#define IDIM 8192
#define NHEADS 16
#define HEADD 128
#define BATCH 2
#define SEQ 2048
#define MTOK 4096

typedef unsigned short u16;
typedef __bf16 bf16x8 __attribute__((ext_vector_type(8)));
typedef float f32x4 __attribute__((ext_vector_type(4)));
typedef float f32x16 __attribute__((ext_vector_type(16)));
typedef unsigned short u16x8 __attribute__((ext_vector_type(8)));
typedef unsigned int u32x2 __attribute__((ext_vector_type(2)));
typedef unsigned int u32x4 __attribute__((ext_vector_type(4)));
typedef unsigned int uv2 __attribute__((ext_vector_type(2)));

__device__ __forceinline__ u16 f2b(float f) {
  unsigned u = __builtin_bit_cast(unsigned, f);
  u += 0x7FFFu + ((u >> 16) & 1u);
  return (u16)(u >> 16);
}
__device__ __forceinline__ float b2f(u16 b) {
  unsigned u = ((unsigned)b) << 16;
  return __builtin_bit_cast(float, u);
}
__device__ __forceinline__ void gl_lds16(const void* g, void* l) {
  auto gp = (const __attribute__((address_space(1))) unsigned int*)((unsigned long long)g);
  auto lp = (__attribute__((address_space(3))) unsigned int*)((unsigned)(unsigned long long)l);
  __builtin_amdgcn_global_load_lds(gp, lp, 16, 0, 0);
}
__device__ __forceinline__ unsigned cvtpk(float lo, float hi) {
  unsigned r;
  asm("v_cvt_pk_bf16_f32 %0, %1, %2" : "=v"(r) : "v"(lo), "v"(hi));
  return r;
}
// rect XCD mapping: co-resident blocks per XCD form a 4(by) x 8(bx) rectangle.
__device__ __forceinline__ void rect_swz(int gx, int gy, int& bx, int& by) {
  const int bid = blockIdx.y * gx + blockIdx.x;
  const int xcd = bid & 7, ii = bid >> 3;
  const int j = ii & 31, rin = ii >> 5;
  const int rectIdx = rin * 8 + xcd;
  const int nry = gy >> 2;
  const int ry = rectIdx % nry, rx = rectIdx / nry;
  by = ry * 4 + (j >> 3);
  bx = rx * 8 + (j & 7);
}

// ---------------- merged weight transpose-convert: all 7 weights, one launch ----------------
__global__ __launch_bounds__(256) void wtrans_all(const float* __restrict__ wq, const float* __restrict__ wk,
                                                  const float* __restrict__ wv, const float* __restrict__ wo,
                                                  const float* __restrict__ wg, const float* __restrict__ wu,
                                                  const float* __restrict__ wd,
                                                  u16* __restrict__ wqkvT, u16* __restrict__ woT,
                                                  u16* __restrict__ wgT, u16* __restrict__ wuT,
                                                  u16* __restrict__ wdT) {
  int bidf = blockIdx.x;
  const float* W;
  u16* Wt;
  int K, N, rowoff, bx, by;
  if (bidf < 3072) {
    int s = bidf >> 10, r = bidf & 1023;
    W = s == 0 ? wq : (s == 1 ? wk : wv);
    Wt = wqkvT; K = 2048; N = 2048; rowoff = s * 2048;
    bx = r & 31; by = r >> 5;
  } else if (bidf < 4096) {
    int r = bidf - 3072;
    W = wo; Wt = woT; K = 2048; N = 2048; rowoff = 0;
    bx = r & 31; by = r >> 5;
  } else if (bidf < 8192) {
    int r = bidf - 4096;
    W = wg; Wt = wgT; K = 2048; N = 8192; rowoff = 0;
    bx = r & 127; by = r >> 7;
  } else if (bidf < 12288) {
    int r = bidf - 8192;
    W = wu; Wt = wuT; K = 2048; N = 8192; rowoff = 0;
    bx = r & 127; by = r >> 7;
  } else {
    int r = bidf - 12288;
    W = wd; Wt = wdT; K = 8192; N = 2048; rowoff = 0;
    bx = r & 31; by = r >> 5;
  }
  __shared__ float t[64][65];
  int n0 = bx * 64, k0 = by * 64;
  int tid = threadIdx.x;
  int kr = tid >> 4, nc = (tid & 15) * 4;
#pragma unroll
  for (int p = 0; p < 4; p++) {
    float4 v = *(const float4*)&W[(size_t)(k0 + p * 16 + kr) * N + n0 + nc];
    t[nc + 0][p * 16 + kr] = v.x;
    t[nc + 1][p * 16 + kr] = v.y;
    t[nc + 2][p * 16 + kr] = v.z;
    t[nc + 3][p * 16 + kr] = v.w;
  }
  __syncthreads();
  int n = tid >> 2, kq = (tid & 3) * 16;
  u16 tmp[16];
#pragma unroll
  for (int i = 0; i < 16; i++) tmp[i] = f2b(t[n][kq + i]);
  *(u16x8*)&Wt[(size_t)(rowoff + n0 + n) * K + k0 + kq] = *(u16x8*)&tmp[0];
  *(u16x8*)&Wt[(size_t)(rowoff + n0 + n) * K + k0 + kq + 8] = *(u16x8*)&tmp[8];
}

// ---------------- V transpose ----------------
__global__ __launch_bounds__(256) void vtrans_k(const u16* __restrict__ qkv, u16* __restrict__ vt) {
  __shared__ u16 t[32][33];
  int s0 = blockIdx.x * 32, d0 = blockIdx.y * 32, bh = blockIdx.z;
  int b = bh >> 4, h = bh & 15;
  int tx = threadIdx.x, ty = threadIdx.y;
#pragma unroll
  for (int i = 0; i < 4; i++)
    t[ty + i * 8][tx] = qkv[(size_t)(b * SEQ + s0 + ty + i * 8) * 6144 + 4096 + h * HEADD + d0 + tx];
  __syncthreads();
#pragma unroll
  for (int i = 0; i < 4; i++)
    vt[(size_t)(bh * HEADD + d0 + ty + i * 8) * SEQ + s0 + tx] = t[tx][ty + i * 8];
}

// ---------------- RMSNorm: fp32 in -> bf16 out ----------------
__global__ __launch_bounds__(256) void rmsnorm_k(const float* __restrict__ X, const float* __restrict__ W,
                                                 u16* __restrict__ O) {
  int row = blockIdx.x;
  int tid = threadIdx.x;
  const float* x = X + (size_t)row * HDIM;
  float4 v0 = ((const float4*)x)[tid * 2];
  float4 v1 = ((const float4*)x)[tid * 2 + 1];
  float ss = v0.x * v0.x + v0.y * v0.y + v0.z * v0.z + v0.w * v0.w
           + v1.x * v1.x + v1.y * v1.y + v1.z * v1.z + v1.w * v1.w;
#pragma unroll
  for (int off = 32; off > 0; off >>= 1) ss += __shfl_down(ss, off);
  __shared__ float red[4];
  if ((tid & 63) == 0) red[tid >> 6] = ss;
  __syncthreads();
  float rs = rsqrtf((red[0] + red[1] + red[2] + red[3]) * (1.0f / HDIM) + 1e-6f);
  const float* w = W + tid * 8;
  u16* o = O + (size_t)row * HDIM + tid * 8;
  float vals[8] = {v0.x, v0.y, v0.z, v0.w, v1.x, v1.y, v1.z, v1.w};
#pragma unroll
  for (int j = 0; j < 8; j++) o[j] = f2b(w[j] * vals[j] * rs);
}

// =====================================================================================
// gemm_lean v3 (TRIPLE-buffered, round-11 proven): C = A(MxK) * Bt(NxK)^T.
// =====================================================================================
template <int EPI>
__global__ __launch_bounds__(512, 2) void gemm_lean(const u16* __restrict__ A, const u16* __restrict__ Bt,
                                                    int M, int N, int K,
                                                    u16* __restrict__ Cb, float* __restrict__ Cf,
                                                    const float* __restrict__ Res) {
  __shared__ char lds[147456];
  const int tid = threadIdx.x, lane = tid & 63, w = tid >> 6;
  const int wm = w >> 1, wn = w & 1;
  int bx, by;
  rect_swz(gridDim.x, gridDim.y, bx, by);
  const int m0 = by * 256, n0 = bx * 128;
  const int NT = K >> 6;

  const int srow = w * 8 + (lane >> 3);
  const int kko = ((lane & 7) ^ (lane >> 3)) * 8;
  const u16* Asrc = A + (size_t)(m0 + srow) * K + kko;
  const u16* Bsrc = Bt + (size_t)(n0 + srow) * K + kko;
  const int wofs = w * 1024;

#define SSA(buf, kt)                                                                          \
  {                                                                                           \
    gl_lds16(Asrc + (size_t)(kt) * 64, lds + (buf) * 49152 + wofs);                           \
    gl_lds16(Asrc + 64 * (size_t)K + (size_t)(kt) * 64, lds + (buf) * 49152 + 8192 + wofs);   \
    gl_lds16(Asrc + 128 * (size_t)K + (size_t)(kt) * 64, lds + (buf) * 49152 + 16384 + wofs); \
    gl_lds16(Asrc + 192 * (size_t)K + (size_t)(kt) * 64, lds + (buf) * 49152 + 24576 + wofs); \
  }
#define SSB(buf, kt)                                                                         \
  {                                                                                          \
    gl_lds16(Bsrc + (size_t)(kt) * 64, lds + (buf) * 49152 + 32768 + wofs);                  \
    gl_lds16(Bsrc + 64 * (size_t)K + (size_t)(kt) * 64, lds + (buf) * 49152 + 40960 + wofs); \
  }
#define LG0 { asm volatile("s_waitcnt lgkmcnt(0)" ::: "memory"); __builtin_amdgcn_sched_barrier(0); }

  const int l15 = lane & 15, l4 = lane >> 4;
  const int kq0 = ((l4) ^ (l15 & 7)) << 4;
  const int kq1 = ((4 + l4) ^ (l15 & 7)) << 4;
  const int abase = (wm * 64 + l15) * 128;
  const int bbase = 32768 + (wn * 64 + l15) * 128;

  const f32x4 fz = {0.f, 0.f, 0.f, 0.f};
  f32x4 acc[4][4];
#pragma unroll
  for (int i = 0; i < 4; i++)
#pragma unroll
    for (int jj = 0; jj < 4; jj++) acc[i][jj] = fz;
  bf16x8 af0[4], af1[4], b0[4], b1[4];

  SSA(0, 0);
  SSB(0, 0);
  {
    const int t1p = (1 < NT) ? 1 : 0;
    SSA(1, t1p);
    SSB(1, t1p);
  }
  asm volatile("s_waitcnt vmcnt(6)" ::: "memory");
  __builtin_amdgcn_s_barrier();

  for (int t = 0; t < NT; ++t) {
    const int bt = t % 3, bs = (t + 2) % 3;
    const char* Lb = lds + bt * 49152;
    const int t2 = (t + 2 < NT) ? t + 2 : NT - 1;
    // ---------- P0: kh0 ----------
#pragma unroll
    for (int mf = 0; mf < 4; mf++) af0[mf] = *(const bf16x8*)(Lb + abase + mf * 2048 + kq0);
#pragma unroll
    for (int nf = 0; nf < 4; nf++) b0[nf] = *(const bf16x8*)(Lb + bbase + nf * 2048 + kq0);
    SSA(bs, t2);
    SSB(bs, t2);
    LG0;
    __builtin_amdgcn_s_setprio(1);
#pragma unroll
    for (int mf = 0; mf < 4; mf++)
#pragma unroll
      for (int nf = 0; nf < 4; nf++)
        acc[mf][nf] = __builtin_amdgcn_mfma_f32_16x16x32_bf16(af0[mf], b0[nf], acc[mf][nf], 0, 0, 0);
    __builtin_amdgcn_s_setprio(0);
    // ---------- P1: kh1 ----------
#pragma unroll
    for (int mf = 0; mf < 4; mf++) af1[mf] = *(const bf16x8*)(Lb + abase + mf * 2048 + kq1);
#pragma unroll
    for (int nf = 0; nf < 4; nf++) b1[nf] = *(const bf16x8*)(Lb + bbase + nf * 2048 + kq1);
    LG0;
    __builtin_amdgcn_s_setprio(1);
#pragma unroll
    for (int mf = 0; mf < 4; mf++)
#pragma unroll
      for (int nf = 0; nf < 4; nf++)
        acc[mf][nf] = __builtin_amdgcn_mfma_f32_16x16x32_bf16(af1[mf], b1[nf], acc[mf][nf], 0, 0, 0);
    __builtin_amdgcn_s_setprio(0);
    asm volatile("s_waitcnt vmcnt(6)" ::: "memory");
    __builtin_amdgcn_s_barrier();
  }
  asm volatile("s_waitcnt vmcnt(0)" ::: "memory");

#pragma unroll
  for (int mf = 0; mf < 4; mf++) {
#pragma unroll
    for (int jr = 0; jr < 4; jr++) {
      const int m = m0 + wm * 64 + mf * 16 + l4 * 4 + jr;
#pragma unroll
      for (int nf = 0; nf < 4; nf++) {
        const int n = n0 + wn * 64 + nf * 16 + l15;
        float v = acc[mf][nf][jr];
        size_t idx = (size_t)m * N + n;
        if (EPI == 0) {
          Cb[idx] = f2b(v);
        } else {
          Cf[idx] = Res[idx] + v;
        }
      }
    }
  }
#undef SSA
#undef SSB
#undef LG0
}

// =====================================================================================
// gemm_fgu2 (round-8 form, best measured): fused gate+up, 2 fat phases, pins kept.
// =====================================================================================
__global__ __launch_bounds__(512, 2) void gemm_fgu2(const u16* __restrict__ A, const u16* __restrict__ Bg,
                                                    const u16* __restrict__ Bu, u16* __restrict__ G) {
  __shared__ char lds[131072];
  const int tid = threadIdx.x, lane = tid & 63, w = tid >> 6;
  const int wm = w >> 2, wn = w & 3;
  int bx, by;
  rect_swz(64, 16, bx, by);
  const int m0 = by * 256, n0 = bx * 128;
  const int NT = 32;

  const int srow = w * 8 + (lane >> 3);
  const int kko = ((lane & 7) ^ (lane >> 3)) * 8;
  const u16* Asrc = A + (size_t)(m0 + srow) * 2048 + kko;
  const u16* Bgsrc = Bg + (size_t)(n0 + srow) * 2048 + kko;
  const u16* Busrc = Bu + (size_t)(n0 + srow) * 2048 + kko;
  const int wofs = w * 1024;

#define SSA(buf, kt)                                                              \
  {                                                                               \
    gl_lds16(Asrc + (kt) * 64, lds + (buf) * 65536 + wofs);                       \
    gl_lds16(Asrc + 64 * 2048 + (kt) * 64, lds + (buf) * 65536 + 8192 + wofs);    \
    gl_lds16(Asrc + 128 * 2048 + (kt) * 64, lds + (buf) * 65536 + 16384 + wofs);  \
    gl_lds16(Asrc + 192 * 2048 + (kt) * 64, lds + (buf) * 65536 + 24576 + wofs);  \
  }
#define SBGU(buf, kt)                                                             \
  {                                                                               \
    gl_lds16(Bgsrc + (kt) * 64, lds + (buf) * 65536 + 32768 + wofs);              \
    gl_lds16(Bgsrc + 64 * 2048 + (kt) * 64, lds + (buf) * 65536 + 40960 + wofs);  \
    gl_lds16(Busrc + (kt) * 64, lds + (buf) * 65536 + 49152 + wofs);              \
    gl_lds16(Busrc + 64 * 2048 + (kt) * 64, lds + (buf) * 65536 + 57344 + wofs);  \
  }
#define LG0 { asm volatile("s_waitcnt lgkmcnt(0)" ::: "memory"); __builtin_amdgcn_sched_barrier(0); }

  const int l15 = lane & 15, l4 = lane >> 4;
  const int kq0 = ((l4) ^ (l15 & 7)) << 4;
  const int kq1 = ((4 + l4) ^ (l15 & 7)) << 4;
  const int abase = (wm * 128 + l15) * 128;
  const int gbase = 32768 + (wn * 32 + l15) * 128;
  const int ubase = 49152 + (wn * 32 + l15) * 128;

  const f32x4 fz = {0.f, 0.f, 0.f, 0.f};
  f32x4 ag[8][2], au[8][2];
#pragma unroll
  for (int i = 0; i < 8; i++)
#pragma unroll
    for (int jj = 0; jj < 2; jj++) { ag[i][jj] = fz; au[i][jj] = fz; }
  bf16x8 af0[8], af1[8], bg0[2], bg1[2], bu0[2], bu1[2];

  SSA(0, 0);
  SBGU(0, 0);
  asm volatile("s_waitcnt vmcnt(4)" ::: "memory");
  __builtin_amdgcn_s_barrier();

  for (int t = 0; t < NT; ++t) {
    const int buf = t & 1, nb = buf ^ 1;
    const char* Lb = lds + buf * 65536;
    const int t1 = (t + 1 < NT) ? t + 1 : NT - 1;
    // ---------- P0 ----------
#pragma unroll
    for (int mf = 0; mf < 8; mf++) af0[mf] = *(const bf16x8*)(Lb + abase + mf * 2048 + kq0);
    SSA(nb, t1);
    asm volatile("s_waitcnt vmcnt(4)" ::: "memory");
    __builtin_amdgcn_s_barrier();
    bg0[0] = *(const bf16x8*)(Lb + gbase + kq0);
    bg0[1] = *(const bf16x8*)(Lb + gbase + 2048 + kq0);
    bu0[0] = *(const bf16x8*)(Lb + ubase + kq0);
    bu0[1] = *(const bf16x8*)(Lb + ubase + 2048 + kq0);
    bg1[0] = *(const bf16x8*)(Lb + gbase + kq1);
    bg1[1] = *(const bf16x8*)(Lb + gbase + 2048 + kq1);
    bu1[0] = *(const bf16x8*)(Lb + ubase + kq1);
    bu1[1] = *(const bf16x8*)(Lb + ubase + 2048 + kq1);
    LG0;
    __builtin_amdgcn_s_setprio(1);
#pragma unroll
    for (int mf = 0; mf < 8; mf++) {
      ag[mf][0] = __builtin_amdgcn_mfma_f32_16x16x32_bf16(af0[mf], bg0[0], ag[mf][0], 0, 0, 0);
      ag[mf][1] = __builtin_amdgcn_mfma_f32_16x16x32_bf16(af0[mf], bg0[1], ag[mf][1], 0, 0, 0);
      au[mf][0] = __builtin_amdgcn_mfma_f32_16x16x32_bf16(af0[mf], bu0[0], au[mf][0], 0, 0, 0);
      au[mf][1] = __builtin_amdgcn_mfma_f32_16x16x32_bf16(af0[mf], bu0[1], au[mf][1], 0, 0, 0);
    }
    __builtin_amdgcn_s_setprio(0);
    // ---------- P1 ----------
#pragma unroll
    for (int mf = 0; mf < 8; mf++) af1[mf] = *(const bf16x8*)(Lb + abase + mf * 2048 + kq1);
    SBGU(nb, t1);
    asm volatile("s_waitcnt vmcnt(4)" ::: "memory");
    LG0;
    __builtin_amdgcn_s_barrier();
    __builtin_amdgcn_s_setprio(1);
#pragma unroll
    for (int mf = 0; mf < 8; mf++) {
      ag[mf][0] = __builtin_amdgcn_mfma_f32_16x16x32_bf16(af1[mf], bg1[0], ag[mf][0], 0, 0, 0);
      ag[mf][1] = __builtin_amdgcn_mfma_f32_16x16x32_bf16(af1[mf], bg1[1], ag[mf][1], 0, 0, 0);
      au[mf][0] = __builtin_amdgcn_mfma_f32_16x16x32_bf16(af1[mf], bu1[0], au[mf][0], 0, 0, 0);
      au[mf][1] = __builtin_amdgcn_mfma_f32_16x16x32_bf16(af1[mf], bu1[1], au[mf][1], 0, 0, 0);
    }
    __builtin_amdgcn_s_setprio(0);
  }
  asm volatile("s_waitcnt vmcnt(0)" ::: "memory");

  // epilogue: G = f2b(silu(g) * u)
#pragma unroll
  for (int mf = 0; mf < 8; mf++) {
#pragma unroll
    for (int jr = 0; jr < 4; jr++) {
      const int m = m0 + wm * 128 + mf * 16 + l4 * 4 + jr;
#pragma unroll
      for (int nf = 0; nf < 2; nf++) {
        const int n = n0 + wn * 32 + nf * 16 + l15;
        float g = ag[mf][nf][jr];
        float u = au[mf][nf][jr];
        float sg = g / (1.f + __expf(-g));
        G[(size_t)m * IDIM + n] = f2b(sg * u);
      }
    }
  }
#undef SSA
#undef SBGU
#undef LG0
}

// =====================================================================================
// flash attention v4: same swapped-operand 32x32x16 structure, but 256 threads
// (4 waves) x QBLK=128, grid (16,32)=512 -> 2 independent blocks/CU (2 barrier
// domains; m114 cross-block overlap of the serial QK^T->softmax->PV chain).
// =====================================================================================
__global__ __launch_bounds__(256, 2) void attn_k(const u16* __restrict__ qkv, const u16* __restrict__ vt,
                                                 u16* __restrict__ out) {
  __shared__ char Kl[2][16384];
  __shared__ char Vl[2][16384];
  int tid = threadIdx.x, lane = tid & 63, w = tid >> 6;  // w 0..3
  // grid (16,32) = 512 blocks; XCD swizzle: each XCD gets 4 whole bh (4MB KV = its L2)
  int bid = blockIdx.y * 16 + blockIdx.x;
  int swz = (bid & 7) * 64 + (bid >> 3);
  int qb = swz & 15, bh = swz >> 4;
  int b = bh >> 4, h = bh & 15;
  int l31 = lane & 31, hi = lane >> 5;
  const float c = 0.088388347648318447f * 1.4426950408889634f;
  const float RT = 90.51f;

  const int qrow = qb * 128 + w * 32 + l31;
  bf16x8 q[8];
  {
    const u16* qp = qkv + (size_t)(b * SEQ + qrow) * 6144 + h * HEADD + hi * 8;
#pragma unroll
    for (int dt = 0; dt < 8; dt++) q[dt] = *(const bf16x8*)(qp + dt * 16);
  }
  f32x16 o[4];
#pragma unroll
  for (int i = 0; i < 4; i++)
#pragma unroll
    for (int j = 0; j < 16; j++) o[i][j] = 0.f;
  float mrow = -1e30f, lrow = 0.f;

  // staging: 4 waves cover K 64 rows (16/wave) and V 128 rows (32/wave)
#define ASTAGE(buf, t)                                                                     \
  {                                                                                        \
    int kv0_ = (t) * 64;                                                                   \
    _Pragma("unroll") for (int i = 0; i < 4; i++) {                                        \
      int r = w * 16 + i * 4 + (lane >> 4);                                                \
      int col = ((lane & 15) ^ (r & 15)) * 8;                                              \
      const u16* src = qkv + (size_t)(b * SEQ + kv0_ + r) * 6144 + HDIM + h * HEADD + col; \
      gl_lds16(src, &Kl[buf][(w * 16 + i * 4) * 256]);                                     \
    }                                                                                      \
    _Pragma("unroll") for (int i = 0; i < 4; i++) {                                        \
      int d = w * 32 + i * 8 + (lane >> 3);                                                \
      int col = ((lane & 7) ^ (d & 7)) * 8;                                                \
      const u16* src = vt + (size_t)(bh * HEADD + d) * SEQ + kv0_ + col;                   \
      gl_lds16(src, &Vl[buf][(w * 32 + i * 8) * 128]);                                     \
    }                                                                                      \
  }

  ASTAGE(0, 0);
  __syncthreads();

  for (int t = 0; t < SEQ / 64; t++) {
    const int buf = t & 1;
    if (t + 1 < SEQ / 64) ASTAGE(buf ^ 1, t + 1);
    const char* Kb = &Kl[buf][0];
    const char* Vb = &Vl[buf][0];
    f32x16 s0, s1;
#pragma unroll
    for (int j = 0; j < 16; j++) { s0[j] = 0.f; s1[j] = 0.f; }
    const int ksl = l31 & 15;
    __builtin_amdgcn_s_setprio(1);
#pragma unroll
    for (int dt = 0; dt < 8; dt++) {
      bf16x8 k0 = *(const bf16x8*)(Kb + (l31)*256 + (((dt * 2 + hi) ^ ksl) << 4));
      bf16x8 k1 = *(const bf16x8*)(Kb + (32 + l31) * 256 + (((dt * 2 + hi) ^ ksl) << 4));
      s0 = __builtin_amdgcn_mfma_f32_32x32x16_bf16(k0, q[dt], s0, 0, 0, 0);
      s1 = __builtin_amdgcn_mfma_f32_32x32x16_bf16(k1, q[dt], s1, 0, 0, 0);
    }
    __builtin_amdgcn_s_setprio(0);
    float m8[8];
#pragma unroll
    for (int g = 0; g < 4; g++) {
      m8[g] = fmaxf(fmaxf(s0[4 * g], s0[4 * g + 1]), fmaxf(s0[4 * g + 2], s0[4 * g + 3]));
      m8[4 + g] = fmaxf(fmaxf(s1[4 * g], s1[4 * g + 1]), fmaxf(s1[4 * g + 2], s1[4 * g + 3]));
    }
    float vmax = fmaxf(fmaxf(fmaxf(m8[0], m8[1]), fmaxf(m8[2], m8[3])),
                       fmaxf(fmaxf(m8[4], m8[5]), fmaxf(m8[6], m8[7])));
    {
      uv2 pr = __builtin_amdgcn_permlane32_swap(__builtin_bit_cast(unsigned, vmax),
                                                __builtin_bit_cast(unsigned, vmax), false, false);
      vmax = fmaxf(__builtin_bit_cast(float, pr[0]), __builtin_bit_cast(float, pr[1]));
    }
    if (__any(vmax > mrow + RT)) {
      float mnew = fmaxf(mrow, vmax);
      float alpha = exp2f((mrow - mnew) * c);
      mrow = mnew;
      lrow *= alpha;
#pragma unroll
      for (int i = 0; i < 4; i++)
#pragma unroll
        for (int j = 0; j < 16; j++) o[i][j] *= alpha;
    }
    const float mc = mrow * c;
    float r4[4] = {0.f, 0.f, 0.f, 0.f};
#pragma unroll
    for (int j = 0; j < 16; j++) {
      s0[j] = exp2f(s0[j] * c - mc);
      r4[j & 3] += s0[j];
    }
#pragma unroll
    for (int j = 0; j < 16; j++) {
      s1[j] = exp2f(s1[j] * c - mc);
      r4[j & 3] += s1[j];
    }
    float rsum = (r4[0] + r4[1]) + (r4[2] + r4[3]);
    {
      uv2 pr = __builtin_amdgcn_permlane32_swap(__builtin_bit_cast(unsigned, rsum),
                                                __builtin_bit_cast(unsigned, rsum), false, false);
      rsum = __builtin_bit_cast(float, pr[0]) + __builtin_bit_cast(float, pr[1]);
    }
    lrow += rsum;
    bf16x8 pa[4];
#pragma unroll
    for (int half = 0; half < 2; half++) {
      const f32x16& sv = half ? s1 : s0;
#pragma unroll
      for (int blk = 0; blk < 2; blk++) {
        int base = blk * 8;
        unsigned A = cvtpk(sv[base + 0], sv[base + 1]);
        unsigned B = cvtpk(sv[base + 2], sv[base + 3]);
        unsigned C = cvtpk(sv[base + 4], sv[base + 5]);
        unsigned D = cvtpk(sv[base + 6], sv[base + 7]);
        uv2 ac = __builtin_amdgcn_permlane32_swap(A, C, false, false);
        uv2 bd = __builtin_amdgcn_permlane32_swap(B, D, false, false);
        u32x4 w4;
        w4[0] = ac[0]; w4[1] = bd[0]; w4[2] = ac[1]; w4[3] = bd[1];
        pa[half * 2 + blk] = __builtin_bit_cast(bf16x8, w4);
      }
    }
    __builtin_amdgcn_s_setprio(1);
#pragma unroll
    for (int dt4 = 0; dt4 < 4; dt4++) {
      const char* vbase = Vb + (dt4 * 32 + l31) * 128;
      const int vsl = l31 & 7;
#pragma unroll
      for (int ks = 0; ks < 4; ks++) {
        bf16x8 vb = *(const bf16x8*)(vbase + (((ks * 2 + hi) ^ vsl) << 4));
        o[dt4] = __builtin_amdgcn_mfma_f32_32x32x16_bf16(vb, pa[ks], o[dt4], 0, 0, 0);
      }
    }
    __builtin_amdgcn_s_setprio(0);
    __syncthreads();
  }
#undef ASTAGE

  const float linv = 1.0f / lrow;
  u16* orow = out + (size_t)(b * SEQ + qrow) * HDIM + h * HEADD;
#pragma unroll
  for (int dt4 = 0; dt4 < 4; dt4++) {
#pragma unroll
    for (int g = 0; g < 4; g++) {
      u32x2 st;
      st[0] = cvtpk(o[dt4][4 * g + 0] * linv, o[dt4][4 * g + 1] * linv);
      st[1] = cvtpk(o[dt4][4 * g + 2] * linv, o[dt4][4 * g + 3] * linv);
      *(u32x2*)(orow + dt4 * 32 + 8 * g + 4 * hi) = st;
    }
  }
}

extern "C" void kernel_launch(void* const* d_in, const int* in_sizes, int n_in,
                              void* d_out, int out_size, void* d_ws, size_t ws_size,
                              hipStream_t stream) {
  const float* hs  = (const float*)d_in[0];
  const float* wq  = (const float*)d_in[1];
  const float* wk  = (const float*)d_in[2];
  const float* wv  = (const float*)d_in[3];
  const float* wo  = (const float*)d_in[4];
  const float* wg  = (const float*)d_in[5];
  const float* wu  = (const float*)d_in[6];
  const float* wd  = (const float*)d_in[7];
  const float* ln1 = (const float*)d_in[8];
  const float* ln2 = (const float*)d_in[9];
  char* ws = (char*)d_ws;
  u16*   wqkvT = (u16*)(ws);
  u16*   woT   = (u16*)(ws + 25165824ull);
  u16*   wgT   = (u16*)(ws + 33554432ull);
  u16*   wuT   = (u16*)(ws + 67108864ull);
  u16*   wdT   = (u16*)(ws + 100663296ull);
  u16*   xb    = (u16*)(ws + 134217728ull);
  float* hid   = (float*)(ws + 150994944ull);
  u16*   qkv   = (u16*)(ws + 184549376ull);
  u16*   vtb   = (u16*)(ws + 234881024ull);
  u16*   attn  = (u16*)(ws + 251658368ull);
  u16*   g     = qkv;  // alias M x I bf16 over qkv+vt region

  wtrans_all<<<16384, 256, 0, stream>>>(wq, wk, wv, wo, wg, wu, wd, wqkvT, woT, wgT, wuT, wdT);

  rmsnorm_k<<<MTOK, 256, 0, stream>>>(hs, ln1, xb);
  gemm_lean<0><<<dim3(48, 16), 512, 0, stream>>>(xb, wqkvT, MTOK, 6144, HDIM, qkv, nullptr, nullptr);
  vtrans_k<<<dim3(64, 4, 32), dim3(32, 8), 0, stream>>>(qkv, vtb);
  attn_k<<<dim3(16, 32), 256, 0, stream>>>(qkv, vtb, attn);
  gemm_lean<3><<<dim3(16, 16), 512, 0, stream>>>(attn, woT, MTOK, HDIM, HDIM, nullptr, hid, hs);
  rmsnorm_k<<<MTOK, 256, 0, stream>>>(hid, ln2, xb);
  gemm_fgu2<<<dim3(64, 16), 512, 0, stream>>>(xb, wgT, wuT, g);
  gemm_lean<3><<<dim3(16, 16), 512, 0, stream>>>(g, wdT, MTOK, HDIM, IDIM, nullptr, (float*)d_out, hid);
}

// Round 16
// 699.912 us; speedup vs baseline: 1.0094x; 1.0094x over previous
//
#include <hip/hip_runtime.h>
#include <hip/hip_bf16.h>

#define HDIM 2048
#define IDIM 8192
#define NHEADS 16
#define HEADD 128
#define BATCH 2
#define SEQ 2048
#define MTOK 4096

typedef unsigned short u16;
typedef __bf16 bf16x8 __attribute__((ext_vector_type(8)));
typedef float f32x4 __attribute__((ext_vector_type(4)));
typedef float f32x16 __attribute__((ext_vector_type(16)));
typedef unsigned short u16x8 __attribute__((ext_vector_type(8)));
typedef unsigned int u32x2 __attribute__((ext_vector_type(2)));
typedef unsigned int u32x4 __attribute__((ext_vector_type(4)));
typedef unsigned int uv2 __attribute__((ext_vector_type(2)));

__device__ __forceinline__ u16 f2b(float f) {
  unsigned u = __builtin_bit_cast(unsigned, f);
  u += 0x7FFFu + ((u >> 16) & 1u);
  return (u16)(u >> 16);
}
__device__ __forceinline__ float b2f(u16 b) {
  unsigned u = ((unsigned)b) << 16;
  return __builtin_bit_cast(float, u);
}
__device__ __forceinline__ void gl_lds16(const void* g, void* l) {
  auto gp = (const __attribute__((address_space(1))) unsigned int*)((unsigned long long)g);
  auto lp = (__attribute__((address_space(3))) unsigned int*)((unsigned)(unsigned long long)l);
  __builtin_amdgcn_global_load_lds(gp, lp, 16, 0, 0);
}
__device__ __forceinline__ unsigned cvtpk(float lo, float hi) {
  unsigned r;
  asm("v_cvt_pk_bf16_f32 %0, %1, %2" : "=v"(r) : "v"(lo), "v"(hi));
  return r;
}
// rect XCD mapping: co-resident blocks per XCD form a 4(by) x 8(bx) rectangle.
__device__ __forceinline__ void rect_swz(int gx, int gy, int& bx, int& by) {
  const int bid = blockIdx.y * gx + blockIdx.x;
  const int xcd = bid & 7, ii = bid >> 3;
  const int j = ii & 31, rin = ii >> 5;
  const int rectIdx = rin * 8 + xcd;
  const int nry = gy >> 2;
  const int ry = rectIdx % nry, rx = rectIdx / nry;
  by = ry * 4 + (j >> 3);
  bx = rx * 8 + (j & 7);
}

// ---------------- merged weight transpose-convert: all 7 weights, one launch ----------------
__global__ __launch_bounds__(256) void wtrans_all(const float* __restrict__ wq, const float* __restrict__ wk,
                                                  const float* __restrict__ wv, const float* __restrict__ wo,
                                                  const float* __restrict__ wg, const float* __restrict__ wu,
                                                  const float* __restrict__ wd,
                                                  u16* __restrict__ wqkvT, u16* __restrict__ woT,
                                                  u16* __restrict__ wgT, u16* __restrict__ wuT,
                                                  u16* __restrict__ wdT) {
  int bidf = blockIdx.x;
  const float* W;
  u16* Wt;
  int K, N, rowoff, bx, by;
  if (bidf < 3072) {
    int s = bidf >> 10, r = bidf & 1023;
    W = s == 0 ? wq : (s == 1 ? wk : wv);
    Wt = wqkvT; K = 2048; N = 2048; rowoff = s * 2048;
    bx = r & 31; by = r >> 5;
  } else if (bidf < 4096) {
    int r = bidf - 3072;
    W = wo; Wt = woT; K = 2048; N = 2048; rowoff = 0;
    bx = r & 31; by = r >> 5;
  } else if (bidf < 8192) {
    int r = bidf - 4096;
    W = wg; Wt = wgT; K = 2048; N = 8192; rowoff = 0;
    bx = r & 127; by = r >> 7;
  } else if (bidf < 12288) {
    int r = bidf - 8192;
    W = wu; Wt = wuT; K = 2048; N = 8192; rowoff = 0;
    bx = r & 127; by = r >> 7;
  } else {
    int r = bidf - 12288;
    W = wd; Wt = wdT; K = 8192; N = 2048; rowoff = 0;
    bx = r & 31; by = r >> 5;
  }
  __shared__ float t[64][65];
  int n0 = bx * 64, k0 = by * 64;
  int tid = threadIdx.x;
  int kr = tid >> 4, nc = (tid & 15) * 4;
#pragma unroll
  for (int p = 0; p < 4; p++) {
    float4 v = *(const float4*)&W[(size_t)(k0 + p * 16 + kr) * N + n0 + nc];
    t[nc + 0][p * 16 + kr] = v.x;
    t[nc + 1][p * 16 + kr] = v.y;
    t[nc + 2][p * 16 + kr] = v.z;
    t[nc + 3][p * 16 + kr] = v.w;
  }
  __syncthreads();
  int n = tid >> 2, kq = (tid & 3) * 16;
  u16 tmp[16];
#pragma unroll
  for (int i = 0; i < 16; i++) tmp[i] = f2b(t[n][kq + i]);
  *(u16x8*)&Wt[(size_t)(rowoff + n0 + n) * K + k0 + kq] = *(u16x8*)&tmp[0];
  *(u16x8*)&Wt[(size_t)(rowoff + n0 + n) * K + k0 + kq + 8] = *(u16x8*)&tmp[8];
}

// ---------------- V transpose ----------------
__global__ __launch_bounds__(256) void vtrans_k(const u16* __restrict__ qkv, u16* __restrict__ vt) {
  __shared__ u16 t[32][33];
  int s0 = blockIdx.x * 32, d0 = blockIdx.y * 32, bh = blockIdx.z;
  int b = bh >> 4, h = bh & 15;
  int tx = threadIdx.x, ty = threadIdx.y;
#pragma unroll
  for (int i = 0; i < 4; i++)
    t[ty + i * 8][tx] = qkv[(size_t)(b * SEQ + s0 + ty + i * 8) * 6144 + 4096 + h * HEADD + d0 + tx];
  __syncthreads();
#pragma unroll
  for (int i = 0; i < 4; i++)
    vt[(size_t)(bh * HEADD + d0 + ty + i * 8) * SEQ + s0 + tx] = t[tx][ty + i * 8];
}

// ---------------- RMSNorm: fp32 in -> bf16 out ----------------
__global__ __launch_bounds__(256) void rmsnorm_k(const float* __restrict__ X, const float* __restrict__ W,
                                                 u16* __restrict__ O) {
  int row = blockIdx.x;
  int tid = threadIdx.x;
  const float* x = X + (size_t)row * HDIM;
  float4 v0 = ((const float4*)x)[tid * 2];
  float4 v1 = ((const float4*)x)[tid * 2 + 1];
  float ss = v0.x * v0.x + v0.y * v0.y + v0.z * v0.z + v0.w * v0.w
           + v1.x * v1.x + v1.y * v1.y + v1.z * v1.z + v1.w * v1.w;
#pragma unroll
  for (int off = 32; off > 0; off >>= 1) ss += __shfl_down(ss, off);
  __shared__ float red[4];
  if ((tid & 63) == 0) red[tid >> 6] = ss;
  __syncthreads();
  float rs = rsqrtf((red[0] + red[1] + red[2] + red[3]) * (1.0f / HDIM) + 1e-6f);
  const float* w = W + tid * 8;
  u16* o = O + (size_t)row * HDIM + tid * 8;
  float vals[8] = {v0.x, v0.y, v0.z, v0.w, v1.x, v1.y, v1.z, v1.w};
#pragma unroll
  for (int j = 0; j < 8; j++) o[j] = f2b(w[j] * vals[j] * rs);
}

// =====================================================================================
// gemm_lean v3 (TRIPLE-buffered, round-11 proven): C = A(MxK) * Bt(NxK)^T.
// BM=256, BN=128, BK=64; 8 waves 4M x 2N; LDS 144KB = 3 buf; 1 barrier/tile;
// counted vmcnt(6); ~4 phases landing slack. EPI: 0 bf16; 3 Cf = Res + v.
// =====================================================================================
template <int EPI>
__global__ __launch_bounds__(512, 2) void gemm_lean(const u16* __restrict__ A, const u16* __restrict__ Bt,
                                                    int M, int N, int K,
                                                    u16* __restrict__ Cb, float* __restrict__ Cf,
                                                    const float* __restrict__ Res) {
  __shared__ char lds[147456];
  const int tid = threadIdx.x, lane = tid & 63, w = tid >> 6;
  const int wm = w >> 1, wn = w & 1;
  int bx, by;
  rect_swz(gridDim.x, gridDim.y, bx, by);
  const int m0 = by * 256, n0 = bx * 128;
  const int NT = K >> 6;

  const int srow = w * 8 + (lane >> 3);
  const int kko = ((lane & 7) ^ (lane >> 3)) * 8;
  const u16* Asrc = A + (size_t)(m0 + srow) * K + kko;
  const u16* Bsrc = Bt + (size_t)(n0 + srow) * K + kko;
  const int wofs = w * 1024;

#define SSA(buf, kt)                                                                          \
  {                                                                                           \
    gl_lds16(Asrc + (size_t)(kt) * 64, lds + (buf) * 49152 + wofs);                           \
    gl_lds16(Asrc + 64 * (size_t)K + (size_t)(kt) * 64, lds + (buf) * 49152 + 8192 + wofs);   \
    gl_lds16(Asrc + 128 * (size_t)K + (size_t)(kt) * 64, lds + (buf) * 49152 + 16384 + wofs); \
    gl_lds16(Asrc + 192 * (size_t)K + (size_t)(kt) * 64, lds + (buf) * 49152 + 24576 + wofs); \
  }
#define SSB(buf, kt)                                                                         \
  {                                                                                          \
    gl_lds16(Bsrc + (size_t)(kt) * 64, lds + (buf) * 49152 + 32768 + wofs);                  \
    gl_lds16(Bsrc + 64 * (size_t)K + (size_t)(kt) * 64, lds + (buf) * 49152 + 40960 + wofs); \
  }
#define LG0 { asm volatile("s_waitcnt lgkmcnt(0)" ::: "memory"); __builtin_amdgcn_sched_barrier(0); }

  const int l15 = lane & 15, l4 = lane >> 4;
  const int kq0 = ((l4) ^ (l15 & 7)) << 4;
  const int kq1 = ((4 + l4) ^ (l15 & 7)) << 4;
  const int abase = (wm * 64 + l15) * 128;
  const int bbase = 32768 + (wn * 64 + l15) * 128;

  const f32x4 fz = {0.f, 0.f, 0.f, 0.f};
  f32x4 acc[4][4];
#pragma unroll
  for (int i = 0; i < 4; i++)
#pragma unroll
    for (int jj = 0; jj < 4; jj++) acc[i][jj] = fz;
  bf16x8 af0[4], af1[4], b0[4], b1[4];

  SSA(0, 0);
  SSB(0, 0);
  {
    const int t1p = (1 < NT) ? 1 : 0;
    SSA(1, t1p);
    SSB(1, t1p);
  }
  asm volatile("s_waitcnt vmcnt(6)" ::: "memory");
  __builtin_amdgcn_s_barrier();

  for (int t = 0; t < NT; ++t) {
    const int bt = t % 3, bs = (t + 2) % 3;
    const char* Lb = lds + bt * 49152;
    const int t2 = (t + 2 < NT) ? t + 2 : NT - 1;
    // ---------- P0: kh0 ----------
#pragma unroll
    for (int mf = 0; mf < 4; mf++) af0[mf] = *(const bf16x8*)(Lb + abase + mf * 2048 + kq0);
#pragma unroll
    for (int nf = 0; nf < 4; nf++) b0[nf] = *(const bf16x8*)(Lb + bbase + nf * 2048 + kq0);
    SSA(bs, t2);
    SSB(bs, t2);
    LG0;
    __builtin_amdgcn_s_setprio(1);
#pragma unroll
    for (int mf = 0; mf < 4; mf++)
#pragma unroll
      for (int nf = 0; nf < 4; nf++)
        acc[mf][nf] = __builtin_amdgcn_mfma_f32_16x16x32_bf16(af0[mf], b0[nf], acc[mf][nf], 0, 0, 0);
    __builtin_amdgcn_s_setprio(0);
    // ---------- P1: kh1 ----------
#pragma unroll
    for (int mf = 0; mf < 4; mf++) af1[mf] = *(const bf16x8*)(Lb + abase + mf * 2048 + kq1);
#pragma unroll
    for (int nf = 0; nf < 4; nf++) b1[nf] = *(const bf16x8*)(Lb + bbase + nf * 2048 + kq1);
    LG0;
    __builtin_amdgcn_s_setprio(1);
#pragma unroll
    for (int mf = 0; mf < 4; mf++)
#pragma unroll
      for (int nf = 0; nf < 4; nf++)
        acc[mf][nf] = __builtin_amdgcn_mfma_f32_16x16x32_bf16(af1[mf], b1[nf], acc[mf][nf], 0, 0, 0);
    __builtin_amdgcn_s_setprio(0);
    asm volatile("s_waitcnt vmcnt(6)" ::: "memory");
    __builtin_amdgcn_s_barrier();
  }
  asm volatile("s_waitcnt vmcnt(0)" ::: "memory");

#pragma unroll
  for (int mf = 0; mf < 4; mf++) {
#pragma unroll
    for (int jr = 0; jr < 4; jr++) {
      const int m = m0 + wm * 64 + mf * 16 + l4 * 4 + jr;
#pragma unroll
      for (int nf = 0; nf < 4; nf++) {
        const int n = n0 + wn * 64 + nf * 16 + l15;
        float v = acc[mf][nf][jr];
        size_t idx = (size_t)m * N + n;
        if (EPI == 0) {
          Cb[idx] = f2b(v);
        } else {
          Cf[idx] = Res[idx] + v;
        }
      }
    }
  }
#undef SSA
#undef SSB
#undef LG0
}

// =====================================================================================
// gemm_fgu2 (round-8 form, best measured): fused gate+up, 2 fat phases, pins kept.
// =====================================================================================
__global__ __launch_bounds__(512, 2) void gemm_fgu2(const u16* __restrict__ A, const u16* __restrict__ Bg,
                                                    const u16* __restrict__ Bu, u16* __restrict__ G) {
  __shared__ char lds[131072];
  const int tid = threadIdx.x, lane = tid & 63, w = tid >> 6;
  const int wm = w >> 2, wn = w & 3;
  int bx, by;
  rect_swz(64, 16, bx, by);
  const int m0 = by * 256, n0 = bx * 128;
  const int NT = 32;

  const int srow = w * 8 + (lane >> 3);
  const int kko = ((lane & 7) ^ (lane >> 3)) * 8;
  const u16* Asrc = A + (size_t)(m0 + srow) * 2048 + kko;
  const u16* Bgsrc = Bg + (size_t)(n0 + srow) * 2048 + kko;
  const u16* Busrc = Bu + (size_t)(n0 + srow) * 2048 + kko;
  const int wofs = w * 1024;

#define SSA(buf, kt)                                                              \
  {                                                                               \
    gl_lds16(Asrc + (kt) * 64, lds + (buf) * 65536 + wofs);                       \
    gl_lds16(Asrc + 64 * 2048 + (kt) * 64, lds + (buf) * 65536 + 8192 + wofs);    \
    gl_lds16(Asrc + 128 * 2048 + (kt) * 64, lds + (buf) * 65536 + 16384 + wofs);  \
    gl_lds16(Asrc + 192 * 2048 + (kt) * 64, lds + (buf) * 65536 + 24576 + wofs);  \
  }
#define SBGU(buf, kt)                                                             \
  {                                                                               \
    gl_lds16(Bgsrc + (kt) * 64, lds + (buf) * 65536 + 32768 + wofs);              \
    gl_lds16(Bgsrc + 64 * 2048 + (kt) * 64, lds + (buf) * 65536 + 40960 + wofs);  \
    gl_lds16(Busrc + (kt) * 64, lds + (buf) * 65536 + 49152 + wofs);              \
    gl_lds16(Busrc + 64 * 2048 + (kt) * 64, lds + (buf) * 65536 + 57344 + wofs);  \
  }
#define LG0 { asm volatile("s_waitcnt lgkmcnt(0)" ::: "memory"); __builtin_amdgcn_sched_barrier(0); }

  const int l15 = lane & 15, l4 = lane >> 4;
  const int kq0 = ((l4) ^ (l15 & 7)) << 4;
  const int kq1 = ((4 + l4) ^ (l15 & 7)) << 4;
  const int abase = (wm * 128 + l15) * 128;
  const int gbase = 32768 + (wn * 32 + l15) * 128;
  const int ubase = 49152 + (wn * 32 + l15) * 128;

  const f32x4 fz = {0.f, 0.f, 0.f, 0.f};
  f32x4 ag[8][2], au[8][2];
#pragma unroll
  for (int i = 0; i < 8; i++)
#pragma unroll
    for (int jj = 0; jj < 2; jj++) { ag[i][jj] = fz; au[i][jj] = fz; }
  bf16x8 af0[8], af1[8], bg0[2], bg1[2], bu0[2], bu1[2];

  SSA(0, 0);
  SBGU(0, 0);
  asm volatile("s_waitcnt vmcnt(4)" ::: "memory");
  __builtin_amdgcn_s_barrier();

  for (int t = 0; t < NT; ++t) {
    const int buf = t & 1, nb = buf ^ 1;
    const char* Lb = lds + buf * 65536;
    const int t1 = (t + 1 < NT) ? t + 1 : NT - 1;
    // ---------- P0 ----------
#pragma unroll
    for (int mf = 0; mf < 8; mf++) af0[mf] = *(const bf16x8*)(Lb + abase + mf * 2048 + kq0);
    SSA(nb, t1);
    asm volatile("s_waitcnt vmcnt(4)" ::: "memory");
    __builtin_amdgcn_s_barrier();
    bg0[0] = *(const bf16x8*)(Lb + gbase + kq0);
    bg0[1] = *(const bf16x8*)(Lb + gbase + 2048 + kq0);
    bu0[0] = *(const bf16x8*)(Lb + ubase + kq0);
    bu0[1] = *(const bf16x8*)(Lb + ubase + 2048 + kq0);
    bg1[0] = *(const bf16x8*)(Lb + gbase + kq1);
    bg1[1] = *(const bf16x8*)(Lb + gbase + 2048 + kq1);
    bu1[0] = *(const bf16x8*)(Lb + ubase + kq1);
    bu1[1] = *(const bf16x8*)(Lb + ubase + 2048 + kq1);
    LG0;
    __builtin_amdgcn_s_setprio(1);
#pragma unroll
    for (int mf = 0; mf < 8; mf++) {
      ag[mf][0] = __builtin_amdgcn_mfma_f32_16x16x32_bf16(af0[mf], bg0[0], ag[mf][0], 0, 0, 0);
      ag[mf][1] = __builtin_amdgcn_mfma_f32_16x16x32_bf16(af0[mf], bg0[1], ag[mf][1], 0, 0, 0);
      au[mf][0] = __builtin_amdgcn_mfma_f32_16x16x32_bf16(af0[mf], bu0[0], au[mf][0], 0, 0, 0);
      au[mf][1] = __builtin_amdgcn_mfma_f32_16x16x32_bf16(af0[mf], bu0[1], au[mf][1], 0, 0, 0);
    }
    __builtin_amdgcn_s_setprio(0);
    // ---------- P1 ----------
#pragma unroll
    for (int mf = 0; mf < 8; mf++) af1[mf] = *(const bf16x8*)(Lb + abase + mf * 2048 + kq1);
    SBGU(nb, t1);
    asm volatile("s_waitcnt vmcnt(4)" ::: "memory");
    LG0;
    __builtin_amdgcn_s_barrier();
    __builtin_amdgcn_s_setprio(1);
#pragma unroll
    for (int mf = 0; mf < 8; mf++) {
      ag[mf][0] = __builtin_amdgcn_mfma_f32_16x16x32_bf16(af1[mf], bg1[0], ag[mf][0], 0, 0, 0);
      ag[mf][1] = __builtin_amdgcn_mfma_f32_16x16x32_bf16(af1[mf], bg1[1], ag[mf][1], 0, 0, 0);
      au[mf][0] = __builtin_amdgcn_mfma_f32_16x16x32_bf16(af1[mf], bu1[0], au[mf][0], 0, 0, 0);
      au[mf][1] = __builtin_amdgcn_mfma_f32_16x16x32_bf16(af1[mf], bu1[1], au[mf][1], 0, 0, 0);
    }
    __builtin_amdgcn_s_setprio(0);
  }
  asm volatile("s_waitcnt vmcnt(0)" ::: "memory");

  // epilogue: G = f2b(silu(g) * u)
#pragma unroll
  for (int mf = 0; mf < 8; mf++) {
#pragma unroll
    for (int jr = 0; jr < 4; jr++) {
      const int m = m0 + wm * 128 + mf * 16 + l4 * 4 + jr;
#pragma unroll
      for (int nf = 0; nf < 2; nf++) {
        const int n = n0 + wn * 32 + nf * 16 + l15;
        float g = ag[mf][nf][jr];
        float u = au[mf][nf][jr];
        float sg = g / (1.f + __expf(-g));
        G[(size_t)m * IDIM + n] = f2b(sg * u);
      }
    }
  }
#undef SSA
#undef SBGU
#undef LG0
}

// =====================================================================================
// flash attention (round-4/14 form, best measured): 512 thr, swapped-operand 32x32x16,
// in-register softmax via cvt_pk + permlane32_swap, defer-max, dbuf K/V staging.
// =====================================================================================
__global__ __launch_bounds__(512, 2) void attn_k(const u16* __restrict__ qkv, const u16* __restrict__ vt,
                                                 u16* __restrict__ out) {
  __shared__ char Kl[2][16384];
  __shared__ char Vl[2][16384];
  int tid = threadIdx.x, lane = tid & 63, w = tid >> 6;
  int bid = blockIdx.y * 8 + blockIdx.x;
  int swz = (bid & 7) * 32 + (bid >> 3);
  int qb = swz & 7, bh = swz >> 3;
  int b = bh >> 4, h = bh & 15;
  int l31 = lane & 31, hi = lane >> 5;
  const float c = 0.088388347648318447f * 1.4426950408889634f;
  const float RT = 90.51f;

  const int qrow = qb * 256 + w * 32 + l31;
  bf16x8 q[8];
  {
    const u16* qp = qkv + (size_t)(b * SEQ + qrow) * 6144 + h * HEADD + hi * 8;
#pragma unroll
    for (int dt = 0; dt < 8; dt++) q[dt] = *(const bf16x8*)(qp + dt * 16);
  }
  f32x16 o[4];
#pragma unroll
  for (int i = 0; i < 4; i++)
#pragma unroll
    for (int j = 0; j < 16; j++) o[i][j] = 0.f;
  float mrow = -1e30f, lrow = 0.f;

#define ASTAGE(buf, t)                                                                     \
  {                                                                                        \
    int kv0_ = (t) * 64;                                                                   \
    _Pragma("unroll") for (int i = 0; i < 2; i++) {                                        \
      int r = w * 8 + i * 4 + (lane >> 4);                                                 \
      int col = ((lane & 15) ^ (r & 15)) * 8;                                              \
      const u16* src = qkv + (size_t)(b * SEQ + kv0_ + r) * 6144 + HDIM + h * HEADD + col; \
      gl_lds16(src, &Kl[buf][(w * 8 + i * 4) * 256]);                                      \
    }                                                                                      \
    _Pragma("unroll") for (int i = 0; i < 2; i++) {                                        \
      int d = w * 16 + i * 8 + (lane >> 3);                                                \
      int col = ((lane & 7) ^ (d & 7)) * 8;                                                \
      const u16* src = vt + (size_t)(bh * HEADD + d) * SEQ + kv0_ + col;                   \
      gl_lds16(src, &Vl[buf][(w * 16 + i * 8) * 128]);                                     \
    }                                                                                      \
  }

  ASTAGE(0, 0);
  __syncthreads();

  for (int t = 0; t < SEQ / 64; t++) {
    const int buf = t & 1;
    if (t + 1 < SEQ / 64) ASTAGE(buf ^ 1, t + 1);
    const char* Kb = &Kl[buf][0];
    const char* Vb = &Vl[buf][0];
    f32x16 s0, s1;
#pragma unroll
    for (int j = 0; j < 16; j++) { s0[j] = 0.f; s1[j] = 0.f; }
    const int ksl = l31 & 15;
    __builtin_amdgcn_s_setprio(1);
#pragma unroll
    for (int dt = 0; dt < 8; dt++) {
      bf16x8 k0 = *(const bf16x8*)(Kb + (l31)*256 + (((dt * 2 + hi) ^ ksl) << 4));
      bf16x8 k1 = *(const bf16x8*)(Kb + (32 + l31) * 256 + (((dt * 2 + hi) ^ ksl) << 4));
      s0 = __builtin_amdgcn_mfma_f32_32x32x16_bf16(k0, q[dt], s0, 0, 0, 0);
      s1 = __builtin_amdgcn_mfma_f32_32x32x16_bf16(k1, q[dt], s1, 0, 0, 0);
    }
    __builtin_amdgcn_s_setprio(0);
    float m8[8];
#pragma unroll
    for (int g = 0; g < 4; g++) {
      m8[g] = fmaxf(fmaxf(s0[4 * g], s0[4 * g + 1]), fmaxf(s0[4 * g + 2], s0[4 * g + 3]));
      m8[4 + g] = fmaxf(fmaxf(s1[4 * g], s1[4 * g + 1]), fmaxf(s1[4 * g + 2], s1[4 * g + 3]));
    }
    float vmax = fmaxf(fmaxf(fmaxf(m8[0], m8[1]), fmaxf(m8[2], m8[3])),
                       fmaxf(fmaxf(m8[4], m8[5]), fmaxf(m8[6], m8[7])));
    {
      uv2 pr = __builtin_amdgcn_permlane32_swap(__builtin_bit_cast(unsigned, vmax),
                                                __builtin_bit_cast(unsigned, vmax), false, false);
      vmax = fmaxf(__builtin_bit_cast(float, pr[0]), __builtin_bit_cast(float, pr[1]));
    }
    if (__any(vmax > mrow + RT)) {
      float mnew = fmaxf(mrow, vmax);
      float alpha = exp2f((mrow - mnew) * c);
      mrow = mnew;
      lrow *= alpha;
#pragma unroll
      for (int i = 0; i < 4; i++)
#pragma unroll
        for (int j = 0; j < 16; j++) o[i][j] *= alpha;
    }
    const float mc = mrow * c;
    float r4[4] = {0.f, 0.f, 0.f, 0.f};
#pragma unroll
    for (int j = 0; j < 16; j++) {
      s0[j] = exp2f(s0[j] * c - mc);
      r4[j & 3] += s0[j];
    }
#pragma unroll
    for (int j = 0; j < 16; j++) {
      s1[j] = exp2f(s1[j] * c - mc);
      r4[j & 3] += s1[j];
    }
    float rsum = (r4[0] + r4[1]) + (r4[2] + r4[3]);
    {
      uv2 pr = __builtin_amdgcn_permlane32_swap(__builtin_bit_cast(unsigned, rsum),
                                                __builtin_bit_cast(unsigned, rsum), false, false);
      rsum = __builtin_bit_cast(float, pr[0]) + __builtin_bit_cast(float, pr[1]);
    }
    lrow += rsum;
    bf16x8 pa[4];
#pragma unroll
    for (int half = 0; half < 2; half++) {
      const f32x16& sv = half ? s1 : s0;
#pragma unroll
      for (int blk = 0; blk < 2; blk++) {
        int base = blk * 8;
        unsigned A = cvtpk(sv[base + 0], sv[base + 1]);
        unsigned B = cvtpk(sv[base + 2], sv[base + 3]);
        unsigned C = cvtpk(sv[base + 4], sv[base + 5]);
        unsigned D = cvtpk(sv[base + 6], sv[base + 7]);
        uv2 ac = __builtin_amdgcn_permlane32_swap(A, C, false, false);
        uv2 bd = __builtin_amdgcn_permlane32_swap(B, D, false, false);
        u32x4 w4;
        w4[0] = ac[0]; w4[1] = bd[0]; w4[2] = ac[1]; w4[3] = bd[1];
        pa[half * 2 + blk] = __builtin_bit_cast(bf16x8, w4);
      }
    }
    __builtin_amdgcn_s_setprio(1);
#pragma unroll
    for (int dt4 = 0; dt4 < 4; dt4++) {
      const char* vbase = Vb + (dt4 * 32 + l31) * 128;
      const int vsl = l31 & 7;
#pragma unroll
      for (int ks = 0; ks < 4; ks++) {
        bf16x8 vb = *(const bf16x8*)(vbase + (((ks * 2 + hi) ^ vsl) << 4));
        o[dt4] = __builtin_amdgcn_mfma_f32_32x32x16_bf16(vb, pa[ks], o[dt4], 0, 0, 0);
      }
    }
    __builtin_amdgcn_s_setprio(0);
    __syncthreads();
  }
#undef ASTAGE

  const float linv = 1.0f / lrow;
  u16* orow = out + (size_t)(b * SEQ + qrow) * HDIM + h * HEADD;
#pragma unroll
  for (int dt4 = 0; dt4 < 4; dt4++) {
#pragma unroll
    for (int g = 0; g < 4; g++) {
      u32x2 st;
      st[0] = cvtpk(o[dt4][4 * g + 0] * linv, o[dt4][4 * g + 1] * linv);
      st[1] = cvtpk(o[dt4][4 * g + 2] * linv, o[dt4][4 * g + 3] * linv);
      *(u32x2*)(orow + dt4 * 32 + 8 * g + 4 * hi) = st;
    }
  }
}

extern "C" void kernel_launch(void* const* d_in, const int* in_sizes, int n_in,
                              void* d_out, int out_size, void* d_ws, size_t ws_size,
                              hipStream_t stream) {
  const float* hs  = (const float*)d_in[0];
  const float* wq  = (const float*)d_in[1];
  const float* wk  = (const float*)d_in[2];
  const float* wv  = (const float*)d_in[3];
  const float* wo  = (const float*)d_in[4];
  const float* wg  = (const float*)d_in[5];
  const float* wu  = (const float*)d_in[6];
  const float* wd  = (const float*)d_in[7];
  const float* ln1 = (const float*)d_in[8];
  const float* ln2 = (const float*)d_in[9];
  char* ws = (char*)d_ws;
  u16*   wqkvT = (u16*)(ws);
  u16*   woT   = (u16*)(ws + 25165824ull);
  u16*   wgT   = (u16*)(ws + 33554432ull);
  u16*   wuT   = (u16*)(ws + 67108864ull);
  u16*   wdT   = (u16*)(ws + 100663296ull);
  u16*   xb    = (u16*)(ws + 134217728ull);
  float* hid   = (float*)(ws + 150994944ull);
  u16*   qkv   = (u16*)(ws + 184549376ull);
  u16*   vtb   = (u16*)(ws + 234881024ull);
  u16*   attn  = (u16*)(ws + 251658368ull);
  u16*   g     = qkv;  // alias M x I bf16 over qkv+vt region

  wtrans_all<<<16384, 256, 0, stream>>>(wq, wk, wv, wo, wg, wu, wd, wqkvT, woT, wgT, wuT, wdT);

  rmsnorm_k<<<MTOK, 256, 0, stream>>>(hs, ln1, xb);
  gemm_lean<0><<<dim3(48, 16), 512, 0, stream>>>(xb, wqkvT, MTOK, 6144, HDIM, qkv, nullptr, nullptr);
  vtrans_k<<<dim3(64, 4, 32), dim3(32, 8), 0, stream>>>(qkv, vtb);
  attn_k<<<dim3(8, 32), 512, 0, stream>>>(qkv, vtb, attn);
  gemm_lean<3><<<dim3(16, 16), 512, 0, stream>>>(attn, woT, MTOK, HDIM, HDIM, nullptr, hid, hs);
  rmsnorm_k<<<MTOK, 256, 0, stream>>>(hid, ln2, xb);
  gemm_fgu2<<<dim3(64, 16), 512, 0, stream>>>(xb, wgT, wuT, g);
  gemm_lean<3><<<dim3(16, 16), 512, 0, stream>>>(g, wdT, MTOK, HDIM, IDIM, nullptr, (float*)d_out, hid);
}